// Round 3
// baseline (328.662 us; speedup 1.0000x reference)
//
#include <hip/hip_runtime.h>
#include <math.h>

#define HW      262144   // 512*512
#define NB      64       // batch
#define T_AUD   8192
#define L_TXT   2048
#define DIM     256

// ws layout (floats):
//  [0,192)            vision per-(b,c) sums
//  [192,256)          audio per-b sums
//  [256,256+64*256)   text per-(b,d) sums

__global__ __launch_bounds__(256) void k_vision(const float* __restrict__ vis,
                                                float* __restrict__ wsum) {
    int bx = blockIdx.x;          // 0..1535
    int plane = bx >> 3;          // 0..191  (= b*3+c)
    int chunk = bx & 7;           // 8 chunks of 32768 floats per plane
    const float4* p4 = reinterpret_cast<const float4*>(vis)
                       + (size_t)plane * 65536 + (size_t)chunk * 8192;
    int t = threadIdx.x;
    float s = 0.f;
#pragma unroll
    for (int k = 0; k < 32; ++k) {
        float4 v = p4[t + k * 256];
        s += (v.x + v.y) + (v.z + v.w);
    }
    for (int off = 32; off; off >>= 1) s += __shfl_down(s, off);
    __shared__ float r[4];
    int lane = t & 63, wid = t >> 6;
    if (lane == 0) r[wid] = s;
    __syncthreads();
    if (t == 0) atomicAdd(&wsum[plane], (r[0] + r[1]) + (r[2] + r[3]));
}

__global__ __launch_bounds__(256) void k_audio(const float* __restrict__ audio,
                                               float* __restrict__ asum) {
    int b = blockIdx.x;
    const float4* p4 = reinterpret_cast<const float4*>(audio) + (size_t)b * 2048;
    int t = threadIdx.x;
    float s = 0.f;
#pragma unroll
    for (int k = 0; k < 8; ++k) {
        float4 v = p4[t + k * 256];
        s += (v.x + v.y) + (v.z + v.w);
    }
    for (int off = 32; off; off >>= 1) s += __shfl_down(s, off);
    __shared__ float r[4];
    if ((t & 63) == 0) r[t >> 6] = s;
    __syncthreads();
    if (t == 0) asum[b] = (r[0] + r[1]) + (r[2] + r[3]);
}

__global__ __launch_bounds__(256) void k_text(const int* __restrict__ bytes,
                                              const float* __restrict__ emb,
                                              float* __restrict__ tsum) {
    int bx = blockIdx.x;          // 0..511
    int b = bx >> 3, chunk = bx & 7;  // 8 chunks of 256 tokens
    int t = threadIdx.x;          // = dim d
    __shared__ int ids[256];
    ids[t] = bytes[b * L_TXT + chunk * 256 + t];
    __syncthreads();
    float acc = 0.f;
#pragma unroll 8
    for (int l = 0; l < 256; ++l) acc += emb[ids[l] * DIM + t];
    atomicAdd(&tsum[b * DIM + t], acc);
}

__global__ __launch_bounds__(256) void k_fuse(
        const float* __restrict__ wsum, const float* __restrict__ asum,
        const float* __restrict__ tsum,
        const float* __restrict__ Wv1, const float* __restrict__ bv1,
        const float* __restrict__ Wv2, const float* __restrict__ bv2,
        const float* __restrict__ Wv3, const float* __restrict__ bv3,
        const float* __restrict__ Wa,  const float* __restrict__ ba,
        const float* __restrict__ Wf,  const float* __restrict__ bfb,
        const float* __restrict__ Wg,  const float* __restrict__ bgb,
        float* __restrict__ out) {
    int b = blockIdx.x, t = threadIdx.x;
    __shared__ float sv[3], h1[16], h2[64], comb[256], y1s[128], y2s[128];
    __shared__ float r0[4], r1[4], r2[4];
    __shared__ float s_cg, s_norm;

    if (t < 3) sv[t] = wsum[b * 3 + t] * (1.f / (float)HW);
    __syncthreads();
    if (t < 16) {
        float s = bv1[t] + Wv1[t*3]*sv[0] + Wv1[t*3+1]*sv[1] + Wv1[t*3+2]*sv[2];
        h1[t] = s * (1.f / (1.f + expf(-s)));   // silu
    }
    __syncthreads();
    if (t < 64) {
        float s = bv2[t];
#pragma unroll
        for (int i = 0; i < 16; ++i) s += Wv2[t*16 + i] * h1[i];
        h2[t] = s * (1.f / (1.f + expf(-s)));
    }
    __syncthreads();
    float v = bv3[t];
#pragma unroll
    for (int j = 0; j < 64; ++j) v += Wv3[t*64 + j] * h2[j];
    float tv = tsum[b * DIM + t] * (1.f / (float)L_TXT);
    float am = asum[b] * (1.f / (float)T_AUD);
    float av = am * Wa[t] + ba[t];

    // inner products across dim
    float pvt = v * tv, pta = tv * av, pav = av * v;
    for (int off = 32; off; off >>= 1) {
        pvt += __shfl_down(pvt, off);
        pta += __shfl_down(pta, off);
        pav += __shfl_down(pav, off);
    }
    int lane = t & 63, wid = t >> 6;
    if (lane == 0) { r0[wid] = pvt; r1[wid] = pta; r2[wid] = pav; }
    __syncthreads();
    if (t == 0) {
        float ivt = (r0[0]+r0[1]) + (r0[2]+r0[3]);
        float ita = (r1[0]+r1[1]) + (r1[2]+r1[3]);
        float iav = (r2[0]+r2[1]) + (r2[2]+r2[3]);
        float p = ivt * ita * iav;
        // angle(real p): 0 if p>=0 (cos=1), pi if p<0 (cos=-1)
        s_cg = (p < 0.f) ? -1.f : 1.f;
    }
    __syncthreads();
    float cd = (v + tv + av) * s_cg;
    comb[t] = cd;
    __syncthreads();
    if (t < 128) {
        float s = bfb[t];
#pragma unroll
        for (int k = 0; k < 128; ++k) s += Wf[t*128 + k] * comb[128 + k];
        y1s[t] = comb[t] + tanhf(s);
    }
    __syncthreads();
    if (t < 128) {
        float s = bgb[t];
#pragma unroll
        for (int k = 0; k < 128; ++k) s += Wg[t*128 + k] * y1s[k];
        y2s[t] = comb[128 + t] + tanhf(s);
    }
    __syncthreads();
    float m = (t < 128) ? y1s[t] : y2s[t - 128];
    float ab = fabsf(m);
    for (int off = 32; off; off >>= 1) ab += __shfl_down(ab, off);
    if (lane == 0) r0[wid] = ab;
    __syncthreads();
    if (t == 0) s_norm = fmaxf((r0[0]+r0[1]) + (r0[2]+r0[3]), 1e-12f);
    __syncthreads();
    out[b * DIM + t] = m / s_norm;
    // eta: det(I + m m^T) = 1 + ||m||^2 > 0 -> sign=+1 -> angle/pi = 0
    if (t == 0) out[NB * DIM + b] = 0.f;
}

extern "C" void kernel_launch(void* const* d_in, const int* in_sizes, int n_in,
                              void* d_out, int out_size, void* d_ws, size_t ws_size,
                              hipStream_t stream) {
    const float* vis   = (const float*)d_in[0];
    const float* audio = (const float*)d_in[1];
    const int*   bytes = (const int*)d_in[2];
    const float* Wv1 = (const float*)d_in[3];
    const float* bv1 = (const float*)d_in[4];
    const float* Wv2 = (const float*)d_in[5];
    const float* bv2 = (const float*)d_in[6];
    const float* Wv3 = (const float*)d_in[7];
    const float* bv3 = (const float*)d_in[8];
    const float* emb = (const float*)d_in[9];
    const float* Wa  = (const float*)d_in[10];
    const float* ba  = (const float*)d_in[11];
    const float* Wf  = (const float*)d_in[12];
    const float* bfb = (const float*)d_in[13];
    const float* Wg  = (const float*)d_in[14];
    const float* bgb = (const float*)d_in[15];
    float* out = (float*)d_out;

    float* ws   = (float*)d_ws;
    float* wsum = ws;          // 192
    float* asum = ws + 192;    // 64
    float* tsum = ws + 256;    // 64*256

    hipMemsetAsync(d_ws, 0, (256 + NB * DIM) * sizeof(float), stream);
    k_vision<<<1536, 256, 0, stream>>>(vis, wsum);
    k_audio <<<64,   256, 0, stream>>>(audio, asum);
    k_text  <<<512,  256, 0, stream>>>(bytes, emb, tsum);
    k_fuse  <<<64,   256, 0, stream>>>(wsum, asum, tsum,
                                       Wv1, bv1, Wv2, bv2, Wv3, bv3,
                                       Wa, ba, Wf, bfb, Wg, bgb, out);
}

// Round 4
// 316.189 us; speedup vs baseline: 1.0394x; 1.0394x over previous
//
#include <hip/hip_runtime.h>
#include <math.h>

#define HW      262144   // 512*512
#define NB      64       // batch
#define T_AUD   8192
#define L_TXT   2048
#define DIM     256

// ws layout (floats):
//  [0, 1536)             vision partials  wpart[(b*3+c)*8 + chunk]
//  [2048, 2048+512*256)  text partials    tpart[(b*8+chunk)*256 + d]
// (no zero-init needed: every slot fully written before read)

__global__ __launch_bounds__(256) void k_vision(const float* __restrict__ vis,
                                                float* __restrict__ wpart) {
    int bx = blockIdx.x;          // 0..1535
    int plane = bx >> 3;          // 0..191  (= b*3+c)
    int chunk = bx & 7;           // 8 chunks of 32768 floats per plane
    const float4* p4 = reinterpret_cast<const float4*>(vis)
                       + (size_t)plane * 65536 + (size_t)chunk * 8192;
    int t = threadIdx.x;
    float s = 0.f;
#pragma unroll
    for (int k = 0; k < 32; ++k) {
        float4 v = p4[t + k * 256];
        s += (v.x + v.y) + (v.z + v.w);
    }
    for (int off = 32; off; off >>= 1) s += __shfl_down(s, off);
    __shared__ float r[4];
    int lane = t & 63, wid = t >> 6;
    if (lane == 0) r[wid] = s;
    __syncthreads();
    if (t == 0) wpart[bx] = (r[0] + r[1]) + (r[2] + r[3]);
}

__global__ __launch_bounds__(256) void k_text(const int* __restrict__ bytes,
                                              const float* __restrict__ emb,
                                              float* __restrict__ tpart) {
    int bx = blockIdx.x;              // 0..511
    int b = bx >> 3, chunk = bx & 7;  // 8 chunks of 256 tokens
    int t = threadIdx.x;
    int g = t >> 6, u = t & 63;       // wave id, lane id
    __shared__ int ids[256];
    __shared__ float4 sm[256];
    ids[t] = bytes[b * L_TXT + chunk * 256 + t];
    __syncthreads();
    const float4* emb4 = reinterpret_cast<const float4*>(emb);
    float4 acc = {0.f, 0.f, 0.f, 0.f};
    // wave g handles rows l = g, g+4, ... ; lane u covers dims [4u,4u+4)
    // one global_load_dwordx4 per wave fetches a full 1KB emb row
#pragma unroll 8
    for (int l = g; l < 256; l += 4) {
        float4 e = emb4[(size_t)ids[l] * 64 + u];
        acc.x += e.x; acc.y += e.y; acc.z += e.z; acc.w += e.w;
    }
    sm[t] = acc;
    __syncthreads();
    if (t < 64) {
        float4 a0 = sm[t], a1 = sm[64 + t], a2 = sm[128 + t], a3 = sm[192 + t];
        float4 tot;
        tot.x = (a0.x + a1.x) + (a2.x + a3.x);
        tot.y = (a0.y + a1.y) + (a2.y + a3.y);
        tot.z = (a0.z + a1.z) + (a2.z + a3.z);
        tot.w = (a0.w + a1.w) + (a2.w + a3.w);
        reinterpret_cast<float4*>(tpart)[(size_t)bx * 64 + t] = tot;
    }
}

__global__ __launch_bounds__(256) void k_fuse(
        const float* __restrict__ wpart, const float* __restrict__ audio,
        const float* __restrict__ tpart,
        const float* __restrict__ Wv1, const float* __restrict__ bv1,
        const float* __restrict__ Wv2, const float* __restrict__ bv2,
        const float* __restrict__ Wv3, const float* __restrict__ bv3,
        const float* __restrict__ Wa,  const float* __restrict__ ba,
        const float* __restrict__ Wf,  const float* __restrict__ bfb,
        const float* __restrict__ Wg,  const float* __restrict__ bgb,
        float* __restrict__ out) {
    int b = blockIdx.x, t = threadIdx.x;
    int lane = t & 63, wid = t >> 6;
    __shared__ __align__(16) float h2[64], comb[256], y1s[128];
    __shared__ float sv[3], h1[16], y2s[128];
    __shared__ float r0[4], r1[4], r2[4];
    __shared__ float s_cg, s_norm, s_am;

    // ---- audio mean (inlined; 2048 float4 per batch) ----
    const float4* a4 = reinterpret_cast<const float4*>(audio) + (size_t)b * 2048;
    float s = 0.f;
#pragma unroll
    for (int k = 0; k < 8; ++k) {
        float4 v = a4[t + k * 256];
        s += (v.x + v.y) + (v.z + v.w);
    }
    for (int off = 32; off; off >>= 1) s += __shfl_down(s, off);
    if (lane == 0) r0[wid] = s;
    __syncthreads();
    if (t == 0) s_am = ((r0[0] + r0[1]) + (r0[2] + r0[3])) * (1.f / (float)T_AUD);
    if (t < 3) {
        float ss = 0.f;
#pragma unroll
        for (int j = 0; j < 8; ++j) ss += wpart[(b * 3 + t) * 8 + j];
        sv[t] = ss * (1.f / (float)HW);
    }
    __syncthreads();
    if (t < 16) {
        float z = bv1[t] + Wv1[t*3]*sv[0] + Wv1[t*3+1]*sv[1] + Wv1[t*3+2]*sv[2];
        h1[t] = z * (1.f / (1.f + expf(-z)));   // silu
    }
    __syncthreads();
    if (t < 64) {
        const float4* w4 = reinterpret_cast<const float4*>(Wv2) + t * 4;
        float z = bv2[t];
#pragma unroll
        for (int j = 0; j < 4; ++j) {
            float4 w = w4[j];
            const float4 h = *reinterpret_cast<const float4*>(&h1[4*j]);
            z += w.x*h.x + w.y*h.y + w.z*h.z + w.w*h.w;
        }
        h2[t] = z * (1.f / (1.f + expf(-z)));
    }
    __syncthreads();
    float v = bv3[t];
    {
        const float4* w4 = reinterpret_cast<const float4*>(Wv3) + t * 16;
#pragma unroll
        for (int j = 0; j < 16; ++j) {
            float4 w = w4[j];
            const float4 h = *reinterpret_cast<const float4*>(&h2[4*j]);
            v += w.x*h.x + w.y*h.y + w.z*h.z + w.w*h.w;
        }
    }
    float tv = 0.f;
#pragma unroll
    for (int c = 0; c < 8; ++c) tv += tpart[((size_t)b * 8 + c) * 256 + t];
    tv *= (1.f / (float)L_TXT);
    float av = s_am * Wa[t] + ba[t];

    // inner products across dim
    float pvt = v * tv, pta = tv * av, pav = av * v;
    for (int off = 32; off; off >>= 1) {
        pvt += __shfl_down(pvt, off);
        pta += __shfl_down(pta, off);
        pav += __shfl_down(pav, off);
    }
    if (lane == 0) { r0[wid] = pvt; r1[wid] = pta; r2[wid] = pav; }
    __syncthreads();
    if (t == 0) {
        float ivt = (r0[0]+r0[1]) + (r0[2]+r0[3]);
        float ita = (r1[0]+r1[1]) + (r1[2]+r1[3]);
        float iav = (r2[0]+r2[1]) + (r2[2]+r2[3]);
        float p = ivt * ita * iav;
        s_cg = (p < 0.f) ? -1.f : 1.f;  // cos(angle(real p)) = sign(p)
    }
    __syncthreads();
    comb[t] = (v + tv + av) * s_cg;
    __syncthreads();
    if (t < 128) {
        const float4* w4 = reinterpret_cast<const float4*>(Wf) + t * 32;
        float z = bfb[t];
#pragma unroll
        for (int j = 0; j < 32; ++j) {
            float4 w = w4[j];
            const float4 x = *reinterpret_cast<const float4*>(&comb[128 + 4*j]);
            z += w.x*x.x + w.y*x.y + w.z*x.z + w.w*x.w;
        }
        y1s[t] = comb[t] + tanhf(z);
    }
    __syncthreads();
    if (t < 128) {
        const float4* w4 = reinterpret_cast<const float4*>(Wg) + t * 32;
        float z = bgb[t];
#pragma unroll
        for (int j = 0; j < 32; ++j) {
            float4 w = w4[j];
            const float4 x = *reinterpret_cast<const float4*>(&y1s[4*j]);
            z += w.x*x.x + w.y*x.y + w.z*x.z + w.w*x.w;
        }
        y2s[t] = comb[128 + t] + tanhf(z);
    }
    __syncthreads();
    float m = (t < 128) ? y1s[t] : y2s[t - 128];
    float ab = fabsf(m);
    for (int off = 32; off; off >>= 1) ab += __shfl_down(ab, off);
    if (lane == 0) r0[wid] = ab;
    __syncthreads();
    if (t == 0) s_norm = fmaxf((r0[0]+r0[1]) + (r0[2]+r0[3]), 1e-12f);
    __syncthreads();
    out[b * DIM + t] = m / s_norm;
    // eta: det(I + m m^T) = 1 + ||m||^2 > 0 -> sign=+1 -> angle/pi = 0
    if (t == 0) out[NB * DIM + b] = 0.f;
}

extern "C" void kernel_launch(void* const* d_in, const int* in_sizes, int n_in,
                              void* d_out, int out_size, void* d_ws, size_t ws_size,
                              hipStream_t stream) {
    const float* vis   = (const float*)d_in[0];
    const float* audio = (const float*)d_in[1];
    const int*   bytes = (const int*)d_in[2];
    const float* Wv1 = (const float*)d_in[3];
    const float* bv1 = (const float*)d_in[4];
    const float* Wv2 = (const float*)d_in[5];
    const float* bv2 = (const float*)d_in[6];
    const float* Wv3 = (const float*)d_in[7];
    const float* bv3 = (const float*)d_in[8];
    const float* emb = (const float*)d_in[9];
    const float* Wa  = (const float*)d_in[10];
    const float* ba  = (const float*)d_in[11];
    const float* Wf  = (const float*)d_in[12];
    const float* bfb = (const float*)d_in[13];
    const float* Wg  = (const float*)d_in[14];
    const float* bgb = (const float*)d_in[15];
    float* out = (float*)d_out;

    float* ws    = (float*)d_ws;
    float* wpart = ws;           // 1536 floats
    float* tpart = ws + 2048;    // 512*256 floats (16B-aligned offset)

    k_vision<<<1536, 256, 0, stream>>>(vis, wpart);
    k_text  <<<512,  256, 0, stream>>>(bytes, emb, tpart);
    k_fuse  <<<64,   256, 0, stream>>>(wpart, audio, tpart,
                                       Wv1, bv1, Wv2, bv2, Wv3, bv3,
                                       Wa, ba, Wf, bfb, Wg, bgb, out);
}

// Round 5
// 315.891 us; speedup vs baseline: 1.0404x; 1.0009x over previous
//
#include <hip/hip_runtime.h>
#include <math.h>

#define HW      262144   // 512*512
#define NB      64       // batch
#define T_AUD   8192
#define L_TXT   2048
#define DIM     256

// ws layout (floats):
//  [0, 1536)             vision partials  wpart[(b*3+c)*8 + chunk]
//  [1536, 1600)          audio sums       asum[b]
//  [2048, 2048+512*256)  text partials    tpart[(b*8+chunk)*256 + d]
// (no zero-init needed: every slot fully written before read)

// One kernel for all independent reduction work; role chosen by blockIdx.
//   [0,1536)     vision: plane=bx>>3, chunk=bx&7, 128KB contiguous
//   [1536,2048)  text:   512 blocks, (b,chunk) token-gather
//   [2048,2112)  audio:  64 blocks, one per batch
__global__ __launch_bounds__(256) void k_reduce(const float* __restrict__ vis,
                                                const int* __restrict__ bytes,
                                                const float* __restrict__ emb,
                                                const float* __restrict__ audio,
                                                float* __restrict__ ws) {
    int bx = blockIdx.x;
    int t = threadIdx.x;
    int lane = t & 63, wid = t >> 6;

    if (bx < 1536) {
        // ---------------- vision ----------------
        int plane = bx >> 3;          // 0..191  (= b*3+c)
        int chunk = bx & 7;
        const float4* p4 = reinterpret_cast<const float4*>(vis)
                           + (size_t)plane * 65536 + (size_t)chunk * 8192;
        float s = 0.f;
#pragma unroll
        for (int k = 0; k < 32; ++k) {
            float4 v = p4[t + k * 256];
            s += (v.x + v.y) + (v.z + v.w);
        }
        for (int off = 32; off; off >>= 1) s += __shfl_down(s, off);
        __shared__ float r[4];
        if (lane == 0) r[wid] = s;
        __syncthreads();
        if (t == 0) ws[bx] = (r[0] + r[1]) + (r[2] + r[3]);
    } else if (bx < 2048) {
        // ---------------- text ----------------
        int bb = bx - 1536;               // 0..511
        int b = bb >> 3, chunk = bb & 7;  // 8 chunks of 256 tokens
        int g = wid, u = lane;
        __shared__ int ids[256];
        __shared__ float4 sm[256];
        ids[t] = bytes[b * L_TXT + chunk * 256 + t];
        __syncthreads();
        const float4* emb4 = reinterpret_cast<const float4*>(emb);
        float4 acc = {0.f, 0.f, 0.f, 0.f};
#pragma unroll 8
        for (int l = g; l < 256; l += 4) {
            float4 e = emb4[(size_t)ids[l] * 64 + u];
            acc.x += e.x; acc.y += e.y; acc.z += e.z; acc.w += e.w;
        }
        sm[t] = acc;
        __syncthreads();
        if (t < 64) {
            float4 a0 = sm[t], a1 = sm[64 + t], a2 = sm[128 + t], a3 = sm[192 + t];
            float4 tot;
            tot.x = (a0.x + a1.x) + (a2.x + a3.x);
            tot.y = (a0.y + a1.y) + (a2.y + a3.y);
            tot.z = (a0.z + a1.z) + (a2.z + a3.z);
            tot.w = (a0.w + a1.w) + (a2.w + a3.w);
            reinterpret_cast<float4*>(ws + 2048)[(size_t)bb * 64 + t] = tot;
        }
    } else {
        // ---------------- audio ----------------
        int b = bx - 2048;                // 0..63
        const float4* a4 = reinterpret_cast<const float4*>(audio) + (size_t)b * 2048;
        float s = 0.f;
#pragma unroll
        for (int k = 0; k < 8; ++k) {
            float4 v = a4[t + k * 256];
            s += (v.x + v.y) + (v.z + v.w);
        }
        for (int off = 32; off; off >>= 1) s += __shfl_down(s, off);
        __shared__ float r[4];
        if (lane == 0) r[wid] = s;
        __syncthreads();
        if (t == 0) ws[1536 + b] = (r[0] + r[1]) + (r[2] + r[3]);
    }
}

__global__ __launch_bounds__(256) void k_fuse(
        const float* __restrict__ ws,
        const float* __restrict__ Wv1, const float* __restrict__ bv1,
        const float* __restrict__ Wv2, const float* __restrict__ bv2,
        const float* __restrict__ Wv3, const float* __restrict__ bv3,
        const float* __restrict__ Wa,  const float* __restrict__ ba,
        const float* __restrict__ Wf,  const float* __restrict__ bfb,
        const float* __restrict__ Wg,  const float* __restrict__ bgb,
        float* __restrict__ out) {
    int b = blockIdx.x, t = threadIdx.x;
    int lane = t & 63, wid = t >> 6;
    const float* wpart = ws;
    const float* asum  = ws + 1536;
    const float* tpart = ws + 2048;
    __shared__ __align__(16) float h2[64], comb[256], y1s[128];
    __shared__ float sv[3], h1[16], y2s[128];
    __shared__ float r0[4], r1[4], r2[4];
    __shared__ float s_cg, s_norm;

    float s_am = asum[b] * (1.f / (float)T_AUD);
    if (t < 3) {
        float ss = 0.f;
#pragma unroll
        for (int j = 0; j < 8; ++j) ss += wpart[(b * 3 + t) * 8 + j];
        sv[t] = ss * (1.f / (float)HW);
    }
    __syncthreads();
    if (t < 16) {
        float z = bv1[t] + Wv1[t*3]*sv[0] + Wv1[t*3+1]*sv[1] + Wv1[t*3+2]*sv[2];
        h1[t] = z * (1.f / (1.f + expf(-z)));   // silu
    }
    __syncthreads();
    if (t < 64) {
        const float4* w4 = reinterpret_cast<const float4*>(Wv2) + t * 4;
        float z = bv2[t];
#pragma unroll
        for (int j = 0; j < 4; ++j) {
            float4 w = w4[j];
            const float4 h = *reinterpret_cast<const float4*>(&h1[4*j]);
            z += w.x*h.x + w.y*h.y + w.z*h.z + w.w*h.w;
        }
        h2[t] = z * (1.f / (1.f + expf(-z)));
    }
    __syncthreads();
    float v = bv3[t];
    {
        const float4* w4 = reinterpret_cast<const float4*>(Wv3) + t * 16;
#pragma unroll
        for (int j = 0; j < 16; ++j) {
            float4 w = w4[j];
            const float4 h = *reinterpret_cast<const float4*>(&h2[4*j]);
            v += w.x*h.x + w.y*h.y + w.z*h.z + w.w*h.w;
        }
    }
    float tv = 0.f;
#pragma unroll
    for (int c = 0; c < 8; ++c) tv += tpart[((size_t)b * 8 + c) * 256 + t];
    tv *= (1.f / (float)L_TXT);
    float av = s_am * Wa[t] + ba[t];

    // inner products across dim
    float pvt = v * tv, pta = tv * av, pav = av * v;
    for (int off = 32; off; off >>= 1) {
        pvt += __shfl_down(pvt, off);
        pta += __shfl_down(pta, off);
        pav += __shfl_down(pav, off);
    }
    if (lane == 0) { r0[wid] = pvt; r1[wid] = pta; r2[wid] = pav; }
    __syncthreads();
    if (t == 0) {
        float ivt = (r0[0]+r0[1]) + (r0[2]+r0[3]);
        float ita = (r1[0]+r1[1]) + (r1[2]+r1[3]);
        float iav = (r2[0]+r2[1]) + (r2[2]+r2[3]);
        float p = ivt * ita * iav;
        s_cg = (p < 0.f) ? -1.f : 1.f;  // cos(angle(real p)) = sign(p)
    }
    __syncthreads();
    comb[t] = (v + tv + av) * s_cg;
    __syncthreads();
    if (t < 128) {
        const float4* w4 = reinterpret_cast<const float4*>(Wf) + t * 32;
        float z = bfb[t];
#pragma unroll
        for (int j = 0; j < 32; ++j) {
            float4 w = w4[j];
            const float4 x = *reinterpret_cast<const float4*>(&comb[128 + 4*j]);
            z += w.x*x.x + w.y*x.y + w.z*x.z + w.w*x.w;
        }
        y1s[t] = comb[t] + tanhf(z);
    }
    __syncthreads();
    if (t < 128) {
        const float4* w4 = reinterpret_cast<const float4*>(Wg) + t * 32;
        float z = bgb[t];
#pragma unroll
        for (int j = 0; j < 32; ++j) {
            float4 w = w4[j];
            const float4 x = *reinterpret_cast<const float4*>(&y1s[4*j]);
            z += w.x*x.x + w.y*x.y + w.z*x.z + w.w*x.w;
        }
        y2s[t] = comb[128 + t] + tanhf(z);
    }
    __syncthreads();
    float m = (t < 128) ? y1s[t] : y2s[t - 128];
    float ab = fabsf(m);
    for (int off = 32; off; off >>= 1) ab += __shfl_down(ab, off);
    if (lane == 0) r0[wid] = ab;
    __syncthreads();
    if (t == 0) s_norm = fmaxf((r0[0]+r0[1]) + (r0[2]+r0[3]), 1e-12f);
    __syncthreads();
    out[b * DIM + t] = m / s_norm;
    // eta: det(I + m m^T) = 1 + ||m||^2 > 0 -> sign=+1 -> angle/pi = 0
    if (t == 0) out[NB * DIM + b] = 0.f;
}

extern "C" void kernel_launch(void* const* d_in, const int* in_sizes, int n_in,
                              void* d_out, int out_size, void* d_ws, size_t ws_size,
                              hipStream_t stream) {
    const float* vis   = (const float*)d_in[0];
    const float* audio = (const float*)d_in[1];
    const int*   bytes = (const int*)d_in[2];
    const float* Wv1 = (const float*)d_in[3];
    const float* bv1 = (const float*)d_in[4];
    const float* Wv2 = (const float*)d_in[5];
    const float* bv2 = (const float*)d_in[6];
    const float* Wv3 = (const float*)d_in[7];
    const float* bv3 = (const float*)d_in[8];
    const float* emb = (const float*)d_in[9];
    const float* Wa  = (const float*)d_in[10];
    const float* ba  = (const float*)d_in[11];
    const float* Wf  = (const float*)d_in[12];
    const float* bfb = (const float*)d_in[13];
    const float* Wg  = (const float*)d_in[14];
    const float* bgb = (const float*)d_in[15];
    float* out = (float*)d_out;
    float* ws  = (float*)d_ws;

    k_reduce<<<2112, 256, 0, stream>>>(vis, bytes, emb, audio, ws);
    k_fuse  <<<64,   256, 0, stream>>>(ws,
                                       Wv1, bv1, Wv2, bv2, Wv3, bv3,
                                       Wa, ba, Wf, bfb, Wg, bgb, out);
}